// Round 3
// baseline (348.319 us; speedup 1.0000x reference)
//
#include <hip/hip_runtime.h>

// WaveMaskEncoder — 3-dispatch M-collapsed pipeline (no kPrep, no W table).
//   kEnc: t[bc,d,q,r] = EN2^T . (x[bc,d,:,:] . EN1)      (134 MB R, 9.4 MB W)
//         A-operand read DIRECTLY from global x (in-reg bf16 cvt, no staging);
//         EN1/EN2 converted in-block to LDS.
//   kMD : u[bc,d',q,r] = sum_d M[d'][d] t[bc,d,q,r],
//         M = EN3.DE3 built in-block (fp32 VALU, bf16 round).
//   kDec: out[bc,d',h',w'] = (DE2^T . u[bc,d']) . DE1    (9.4 R, 134 MB W)
//         DE2/DE1 converted in-block to LDS.
//
// MFMA 16x16x32 bf16 layouts (HW-verified per docs m89/m120):
//   A[m][k]: m = lane&15, k = (lane>>4)*8 + j   (8 contiguous k per lane)
//   B[k][n]: n = lane&15, k = (lane>>4)*8 + j   (n-major, k-contig storage)
//   C/D:     col = lane&15, row = (lane>>4)*4 + reg

#define LDIM 128
#define NDIM 48
#define HW   (LDIM * LDIM)     // 16384
#define L3V  (LDIM * HW)       // 2097152
#define QR   2304              // 48*48

typedef __bf16 bf16x8 __attribute__((ext_vector_type(8)));
typedef float  f32x4  __attribute__((ext_vector_type(4)));
typedef unsigned short u16;

// LDS row strides (u16 units); multiples of 8 u16 = 16 B for b128 alignment.
#define S128 136
#define S64  72

__device__ __forceinline__ u16 f2bf(float f) {   // fp32 -> bf16 RNE
    unsigned int u = __builtin_bit_cast(unsigned int, f);
    return (u16)((u + 0x7fffu + ((u >> 16) & 1u)) >> 16);
}
__device__ __forceinline__ bf16x8 frag(const u16* p) {
    return *reinterpret_cast<const bf16x8*>(p);
}
__device__ __forceinline__ f32x4 mfma16(bf16x8 a, bf16x8 b, f32x4 c) {
    return __builtin_amdgcn_mfma_f32_16x16x32_bf16(a, b, c, 0, 0, 0);
}

// ---------------------------------------------------------------- kEnc
// t[(bc*128+d)][q][r] = sum_h EN2[h][q] * (sum_w x[bc][d][h][w] EN1[w][r])
// grid (d=128, bc=16), block 256 = 4 waves, 2 barriers, LDS 39 KB.
__global__ __launch_bounds__(256) void kEnc(const float* __restrict__ x,
                                            const float* __restrict__ EN1,
                                            const float* __restrict__ EN2,
                                            u16* __restrict__ t) {
    __shared__ u16 lW1[48 * S128];   // EN1t [r][w]  (B n-major, k=w contig)
    __shared__ u16 lW2[48 * S128];   // EN2t [q][h]  (A rows,   k=h contig)
    __shared__ u16 lT [48 * S128];   // T    [r][h]  (B n-major, k=h contig)
    const int bc = blockIdx.y, d = blockIdx.x;
    const int tid = threadIdx.x, lane = tid & 63, wv = tid >> 6, quad = lane >> 4;
    const int row = lane & 15, kof = quad * 8;

    // Convert EN1[w=128][r=48] -> lW1[r][w] and EN2[h=128][q=48] -> lW2[q][h].
    // 1536 float4 each; coalesced reads, transposed u16 writes (one-time cost).
    for (int i = tid; i < 1536; i += 256) {
        int w = i / 12, g = i - w * 12, r0 = g * 4;
        float4 v = *reinterpret_cast<const float4*>(EN1 + w * 48 + r0);
        lW1[(r0 + 0) * S128 + w] = f2bf(v.x);
        lW1[(r0 + 1) * S128 + w] = f2bf(v.y);
        lW1[(r0 + 2) * S128 + w] = f2bf(v.z);
        lW1[(r0 + 3) * S128 + w] = f2bf(v.w);
        float4 u = *reinterpret_cast<const float4*>(EN2 + w * 48 + r0);
        lW2[(r0 + 0) * S128 + w] = f2bf(u.x);
        lW2[(r0 + 1) * S128 + w] = f2bf(u.y);
        lW2[(r0 + 2) * S128 + w] = f2bf(u.z);
        lW2[(r0 + 3) * S128 + w] = f2bf(u.w);
    }
    __syncthreads();
    // G_a: T[h][r] = sum_w S[h][w] * EN1[w][r]; wave: h-rows [wv*32,+32).
    // A-frags straight from global x (fp32 -> bf16 in regs); B from lW1.
    {
        const float* xp = x + (size_t)bc * L3V + (size_t)d * HW;
        const int h0 = wv * 32;
        f32x4 acc[2][3] = {};
        for (int kk = 0; kk < 4; ++kk) {
            bf16x8 b[3];
            for (int n = 0; n < 3; ++n)
                b[n] = frag(lW1 + (n * 16 + row) * S128 + kk * 32 + kof);
            for (int m = 0; m < 2; ++m) {
                const float* ap = xp + (h0 + m * 16 + row) * 128 + kk * 32 + kof;
                float4 v0 = *reinterpret_cast<const float4*>(ap);
                float4 v1 = *reinterpret_cast<const float4*>(ap + 4);
                u16 av[8];
                av[0] = f2bf(v0.x); av[1] = f2bf(v0.y); av[2] = f2bf(v0.z); av[3] = f2bf(v0.w);
                av[4] = f2bf(v1.x); av[5] = f2bf(v1.y); av[6] = f2bf(v1.z); av[7] = f2bf(v1.w);
                bf16x8 a = *reinterpret_cast<bf16x8*>(av);
                for (int n = 0; n < 3; ++n) acc[m][n] = mfma16(a, b[n], acc[m][n]);
            }
        }
        // write lT[r][h]; 4 regs = 4 consecutive h -> packed 8B write
        for (int m = 0; m < 2; ++m)
            for (int n = 0; n < 3; ++n) {
                int r = n * 16 + row, h = h0 + m * 16 + quad * 4;
                uint2 pk;
                pk.x = (unsigned)f2bf(acc[m][n][0]) | ((unsigned)f2bf(acc[m][n][1]) << 16);
                pk.y = (unsigned)f2bf(acc[m][n][2]) | ((unsigned)f2bf(acc[m][n][3]) << 16);
                *reinterpret_cast<uint2*>(lT + r * S128 + h) = pk;
            }
    }
    __syncthreads();
    // G_b: A[q][r] = sum_h EN2[h][q] * T[h][r]; waves 0..2, m-tile = wv
    if (wv < 3) {
        const int q0 = wv * 16;
        f32x4 acc[3] = {};
        for (int kk = 0; kk < 4; ++kk) {
            bf16x8 a = frag(lW2 + (q0 + row) * S128 + kk * 32 + kof);
            for (int n = 0; n < 3; ++n) {
                bf16x8 b = frag(lT + (n * 16 + row) * S128 + kk * 32 + kof);
                acc[n] = mfma16(a, b, acc[n]);
            }
        }
        u16* tp = t + (size_t)(bc * 128 + d) * QR;
        for (int n = 0; n < 3; ++n)
            for (int j = 0; j < 4; ++j)
                tp[(q0 + quad * 4 + j) * 48 + n * 16 + row] = f2bf(acc[n][j]);
    }
}

// ---------------------------------------------------------------- kMD
// u[bc][d'][q][r] = sum_d M[d'][d] * t[bc][d][q][r],  M = EN3.DE3 (in-block).
// grid (qr-tiles 36, bc 16), block 256. GEMM m=d'(128) x n=qr(64), K=128.
__global__ __launch_bounds__(256) void kMD(const u16* __restrict__ t,
                                           const float* __restrict__ EN3,
                                           const float* __restrict__ DE3,
                                           u16* __restrict__ u) {
    __shared__ u16 lM[128 * S128];   // M [d'][d]     (A rows, k=d contig)
    __shared__ u16 lB[64 * S128];    // t  [qr][d]    (B n-major, k=d contig)
    const int bc = blockIdx.y, qr0 = blockIdx.x * 64;
    const int tid = threadIdx.x, lane = tid & 63, wv = tid >> 6, quad = lane >> 4;
    const int row = lane & 15, kof = quad * 8;

    // Build M[d'][d] = sum_p EN3[d][p] * DE3[p][d'] (fp32, bf16 round).
    // thread: d' = tid&127 (coalesced in DE3 rows), d in [ (tid>>7)*64, +64 ).
    {
        const int dp = tid & 127, d0 = (tid >> 7) * 64;
        float de3[48];
        for (int p = 0; p < 48; ++p) de3[p] = DE3[p * 128 + dp];
        for (int dd = d0; dd < d0 + 64; ++dd) {
            float s = 0.f;
            for (int pv = 0; pv < 12; ++pv) {
                float4 e = *reinterpret_cast<const float4*>(EN3 + dd * 48 + pv * 4);
                s += e.x * de3[pv * 4 + 0] + e.y * de3[pv * 4 + 1]
                   + e.z * de3[pv * 4 + 2] + e.w * de3[pv * 4 + 3];
            }
            lM[dp * S128 + dd] = f2bf(s);
        }
    }
    // stage t tile [d=128][qr 64] -> lB[qr][d] (transpose via u16 writes)
    {
        const u16* tp = t + (size_t)bc * (128 * QR) + qr0 + (tid & 7) * 8;
        const int d0 = tid >> 3;                  // 0..31
        for (int g = 0; g < 4; ++g) {
            int dd = d0 + g * 32;
            u16 v[8];
            *reinterpret_cast<float4*>(v) = *reinterpret_cast<const float4*>(tp + (size_t)dd * QR);
            for (int j = 0; j < 8; ++j) lB[((tid & 7) * 8 + j) * S128 + dd] = v[j];
        }
    }
    __syncthreads();
    const int m0 = wv * 32;
    f32x4 acc[2][4] = {};
    for (int kk = 0; kk < 4; ++kk) {
        bf16x8 a[2], b[4];
        for (int n = 0; n < 4; ++n)
            b[n] = frag(lB + (n * 16 + row) * S128 + kk * 32 + kof);
        for (int m = 0; m < 2; ++m)
            a[m] = frag(lM + (m0 + m * 16 + row) * S128 + kk * 32 + kof);
        for (int m = 0; m < 2; ++m)
            for (int n = 0; n < 4; ++n) acc[m][n] = mfma16(a[m], b[n], acc[m][n]);
    }
    u16* up = u + (size_t)bc * (128 * QR) + qr0;
    for (int m = 0; m < 2; ++m)
        for (int n = 0; n < 4; ++n)
            for (int j = 0; j < 4; ++j) {
                int dp = m0 + m * 16 + quad * 4 + j;
                up[(size_t)dp * QR + n * 16 + row] = f2bf(acc[m][n][j]);
            }
}

// ---------------------------------------------------------------- kDec
// out[bc][d'][h'][w'] = sum_r (sum_q DE2[q][h'] u[bc][d'][q][r]) * DE1[r][w']
// grid (d'=128, bc=16), block 256 = 4 waves, 2 barriers, LDS 62 KB.
__global__ __launch_bounds__(256) void kDec(const u16* __restrict__ u,
                                            const float* __restrict__ DE2,
                                            const float* __restrict__ DE1,
                                            float* __restrict__ out) {
    __shared__ u16 lU  [48 * S64];   // u^T [r][q pad64]  (B n-major, k=q contig)
    __shared__ u16 lV  [128 * S64];  // V [h'][r pad64]   (A rows, k=r contig)
    __shared__ u16 lWD2[128 * S64];  // DE2t [h'][q pad64] (A rows, k=q contig)
    __shared__ u16 lWD1[128 * S64];  // DE1t [w'][r pad64] (B n-major, k=r contig)
    const int bc = blockIdx.y, dp = blockIdx.x;
    const int tid = threadIdx.x, lane = tid & 63, wv = tid >> 6, quad = lane >> 4;
    const int row = lane & 15, kof = quad * 8;

    // zero K-padding (cols 48..63 of all four tiles' K dims)
    for (int i = tid; i < 48 * 16; i += 256)  lU[(i >> 4) * S64 + 48 + (i & 15)] = 0;
    for (int i = tid; i < 128 * 16; i += 256) {
        int rr = (i >> 4) * S64 + 48 + (i & 15);
        lV[rr] = 0; lWD2[rr] = 0; lWD1[rr] = 0;
    }
    // Convert DE2[q=48][h=128] -> lWD2[h][q] and DE1[r=48][w=128] -> lWD1[w][r].
    for (int i = tid; i < 1536; i += 256) {
        int q = i >> 5, h0 = (i & 31) * 4;
        float4 v = *reinterpret_cast<const float4*>(DE2 + q * 128 + h0);
        lWD2[(h0 + 0) * S64 + q] = f2bf(v.x);
        lWD2[(h0 + 1) * S64 + q] = f2bf(v.y);
        lWD2[(h0 + 2) * S64 + q] = f2bf(v.z);
        lWD2[(h0 + 3) * S64 + q] = f2bf(v.w);
        float4 w = *reinterpret_cast<const float4*>(DE1 + q * 128 + h0);
        lWD1[(h0 + 0) * S64 + q] = f2bf(w.x);
        lWD1[(h0 + 1) * S64 + q] = f2bf(w.y);
        lWD1[(h0 + 2) * S64 + q] = f2bf(w.z);
        lWD1[(h0 + 3) * S64 + q] = f2bf(w.w);
    }
    // stage u[bc][d'][q][r] (4.6 KB) -> lU[r][q] transposed
    {
        const u16* sp = u + (size_t)(bc * 128 + dp) * QR;
        for (int i = tid; i < 288; i += 256) {
            u16 v[8];
            *reinterpret_cast<float4*>(v) = *reinterpret_cast<const float4*>(sp + i * 8);
            int q = i / 6, rb = (i % 6) * 8;
            for (int j = 0; j < 8; ++j) lU[(rb + j) * S64 + q] = v[j];
        }
    }
    __syncthreads();
    // G_a: V[h'][r] = sum_q DE2[q][h'] * u[q][r]; wave: h'-rows [wv*32,+32), K=64
    {
        const int h0 = wv * 32;
        f32x4 acc[2][3] = {};
        for (int kk = 0; kk < 2; ++kk) {
            bf16x8 b[3];
            for (int n = 0; n < 3; ++n)
                b[n] = frag(lU + (n * 16 + row) * S64 + kk * 32 + kof);
            for (int m = 0; m < 2; ++m) {
                bf16x8 a = frag(lWD2 + (h0 + m * 16 + row) * S64 + kk * 32 + kof);
                for (int n = 0; n < 3; ++n) acc[m][n] = mfma16(a, b[n], acc[m][n]);
            }
        }
        for (int m = 0; m < 2; ++m)
            for (int n = 0; n < 3; ++n)
                for (int j = 0; j < 4; ++j)
                    lV[(h0 + m * 16 + quad * 4 + j) * S64 + n * 16 + row] = f2bf(acc[m][n][j]);
    }
    __syncthreads();
    // G_b: out[h'][w'] = sum_r V[h'][r] * DE1[r][w']; K=64, direct fp32 stores
    {
        const int h0 = wv * 32;
        f32x4 acc[2][8] = {};
        for (int kk = 0; kk < 2; ++kk) {
            bf16x8 a[2], b[8];
            for (int n = 0; n < 8; ++n)
                b[n] = frag(lWD1 + (n * 16 + row) * S64 + kk * 32 + kof);
            for (int m = 0; m < 2; ++m)
                a[m] = frag(lV + (h0 + m * 16 + row) * S64 + kk * 32 + kof);
            for (int m = 0; m < 2; ++m)
                for (int n = 0; n < 8; ++n) acc[m][n] = mfma16(a[m], b[n], acc[m][n]);
        }
        float* ob = out + (size_t)bc * L3V + (size_t)dp * HW;
        for (int m = 0; m < 2; ++m)
            for (int n = 0; n < 8; ++n)
                for (int j = 0; j < 4; ++j)
                    ob[(h0 + m * 16 + quad * 4 + j) * 128 + n * 16 + row] = acc[m][n][j];
    }
}

// ---------------------------------------------------------------- launch
extern "C" void kernel_launch(void* const* d_in, const int* in_sizes, int n_in,
                              void* d_out, int out_size, void* d_ws, size_t ws_size,
                              hipStream_t stream) {
    const float* x   = (const float*)d_in[0];
    const float* EN3 = (const float*)d_in[1];
    const float* EN2 = (const float*)d_in[2];
    const float* EN1 = (const float*)d_in[3];
    const float* DE3 = (const float*)d_in[4];
    const float* DE2 = (const float*)d_in[5];
    const float* DE1 = (const float*)d_in[6];
    float* out = (float*)d_out;

    // ws (bytes): t @0 (9,437,184), u @9437184 (9,437,184)
    u16* t = (u16*)d_ws;
    u16* u = (u16*)((char*)d_ws + 9437184);

    kEnc<<<dim3(128, 16), 256, 0, stream>>>(x, EN1, EN2, t);
    kMD <<<dim3(36, 16),  256, 0, stream>>>(t, EN3, DE3, u);
    kDec<<<dim3(128, 16), 256, 0, stream>>>(u, DE2, DE1, out);
}

// Round 4
// 284.337 us; speedup vs baseline: 1.2250x; 1.2250x over previous
//
#include <hip/hip_runtime.h>

// WaveMaskEncoder — 3-dispatch M-collapsed pipeline.
//   kEnc: t[bc,d,q,r] = EN2^T . (x[bc,d,:,:] . EN1)      (134 MB R, 9.4 MB W)
//         A-operand read DIRECTLY from global x (in-reg bf16 cvt);
//         EN1/EN2 converted in-block to LDS.
//         Blocks with d==0 additionally build M[d'][d] = sum_p EN3[d,p]DE3[p,d']
//         (16 blocks x 8 rows each; hidden under the other 2032 blocks).
//   kM  : u[bc,d',q,r] = sum_d M[d'][d] t[bc,d,q,r]  (M via global L2-hot frags)
//   kDec: out[bc,d',h',w'] = (DE2^T . u[bc,d']) . DE1    (9.4 R, 134 MB W)
//
// MFMA 16x16x32 bf16 layouts (HW-verified per docs m89/m120):
//   A[m][k]: m = lane&15, k = (lane>>4)*8 + j   (8 contiguous k per lane)
//   B[k][n]: n = lane&15, k = (lane>>4)*8 + j   (n-major, k-contig storage)
//   C/D:     col = lane&15, row = (lane>>4)*4 + reg

#define LDIM 128
#define NDIM 48
#define HW   (LDIM * LDIM)     // 16384
#define L3V  (LDIM * HW)       // 2097152
#define QR   2304              // 48*48

typedef __bf16 bf16x8 __attribute__((ext_vector_type(8)));
typedef float  f32x4  __attribute__((ext_vector_type(4)));
typedef unsigned short u16;

// LDS row strides (u16 units); multiples of 8 u16 = 16 B for b128 alignment.
#define S128 136
#define S64  72

__device__ __forceinline__ u16 f2bf(float f) {   // fp32 -> bf16 RNE
    unsigned int u = __builtin_bit_cast(unsigned int, f);
    return (u16)((u + 0x7fffu + ((u >> 16) & 1u)) >> 16);
}
__device__ __forceinline__ bf16x8 frag(const u16* p) {
    return *reinterpret_cast<const bf16x8*>(p);
}
__device__ __forceinline__ f32x4 mfma16(bf16x8 a, bf16x8 b, f32x4 c) {
    return __builtin_amdgcn_mfma_f32_16x16x32_bf16(a, b, c, 0, 0, 0);
}

// ---------------------------------------------------------------- kEnc
// t[(bc*128+d)][q][r] = sum_h EN2[h][q] * (sum_w x[bc][d][h][w] EN1[w][r])
// grid (d=128, bc=16), block 256 = 4 waves, 2 barriers, LDS 39 KB.
__global__ __launch_bounds__(256) void kEnc(const float* __restrict__ x,
                                            const float* __restrict__ EN1,
                                            const float* __restrict__ EN2,
                                            const float* __restrict__ EN3,
                                            const float* __restrict__ DE3,
                                            u16* __restrict__ Mw,
                                            u16* __restrict__ t) {
    __shared__ u16 lW1[48 * S128];   // EN1t [r][w]  (B n-major, k=w contig)
    __shared__ u16 lW2[48 * S128];   // EN2t [q][h]  (A rows,   k=h contig)
    __shared__ u16 lT [48 * S128];   // T    [r][h]  (B n-major, k=h contig)
    const int bc = blockIdx.y, d = blockIdx.x;
    const int tid = threadIdx.x, lane = tid & 63, wv = tid >> 6, quad = lane >> 4;
    const int row = lane & 15, kof = quad * 8;

    // ---- Side job (16 blocks with d==0): build M rows [bc*8, bc*8+8).
    // Streaming fp32 dot; EN3 rows broadcast across half-block, DE3 cols L2-hot.
    if (d == 0) {
        const int dd = tid & 127, sub = tid >> 7;   // this thread: col dd, rows dpb+{0,2,4,6}
        const int dpb = bc * 8 + sub;
        float s0 = 0.f, s1 = 0.f, s2 = 0.f, s3 = 0.f;
        for (int p = 0; p < 48; ++p) {
            float e = EN3[dd * 48 + p];
            const float* dr = DE3 + p * 128 + dpb;
            s0 += e * dr[0];
            s1 += e * dr[2];
            s2 += e * dr[4];
            s3 += e * dr[6];
        }
        Mw[(dpb + 0) * 128 + dd] = f2bf(s0);
        Mw[(dpb + 2) * 128 + dd] = f2bf(s1);
        Mw[(dpb + 4) * 128 + dd] = f2bf(s2);
        Mw[(dpb + 6) * 128 + dd] = f2bf(s3);
    }

    // Convert EN1[w=128][r=48] -> lW1[r][w] and EN2[h=128][q=48] -> lW2[q][h].
    for (int i = tid; i < 1536; i += 256) {
        int w = i / 12, g = i - w * 12, r0 = g * 4;
        float4 v = *reinterpret_cast<const float4*>(EN1 + w * 48 + r0);
        lW1[(r0 + 0) * S128 + w] = f2bf(v.x);
        lW1[(r0 + 1) * S128 + w] = f2bf(v.y);
        lW1[(r0 + 2) * S128 + w] = f2bf(v.z);
        lW1[(r0 + 3) * S128 + w] = f2bf(v.w);
        float4 u = *reinterpret_cast<const float4*>(EN2 + w * 48 + r0);
        lW2[(r0 + 0) * S128 + w] = f2bf(u.x);
        lW2[(r0 + 1) * S128 + w] = f2bf(u.y);
        lW2[(r0 + 2) * S128 + w] = f2bf(u.z);
        lW2[(r0 + 3) * S128 + w] = f2bf(u.w);
    }
    __syncthreads();
    // G_a: T[h][r] = sum_w S[h][w] * EN1[w][r]; wave: h-rows [wv*32,+32).
    // A-frags straight from global x (fp32 -> bf16 in regs); B from lW1.
    {
        const float* xp = x + (size_t)bc * L3V + (size_t)d * HW;
        const int h0 = wv * 32;
        f32x4 acc[2][3] = {};
        for (int kk = 0; kk < 4; ++kk) {
            bf16x8 b[3];
            for (int n = 0; n < 3; ++n)
                b[n] = frag(lW1 + (n * 16 + row) * S128 + kk * 32 + kof);
            for (int m = 0; m < 2; ++m) {
                const float* ap = xp + (h0 + m * 16 + row) * 128 + kk * 32 + kof;
                float4 v0 = *reinterpret_cast<const float4*>(ap);
                float4 v1 = *reinterpret_cast<const float4*>(ap + 4);
                u16 av[8];
                av[0] = f2bf(v0.x); av[1] = f2bf(v0.y); av[2] = f2bf(v0.z); av[3] = f2bf(v0.w);
                av[4] = f2bf(v1.x); av[5] = f2bf(v1.y); av[6] = f2bf(v1.z); av[7] = f2bf(v1.w);
                bf16x8 a = *reinterpret_cast<bf16x8*>(av);
                for (int n = 0; n < 3; ++n) acc[m][n] = mfma16(a, b[n], acc[m][n]);
            }
        }
        // write lT[r][h]; 4 regs = 4 consecutive h -> packed 8B write
        for (int m = 0; m < 2; ++m)
            for (int n = 0; n < 3; ++n) {
                int r = n * 16 + row, h = h0 + m * 16 + quad * 4;
                uint2 pk;
                pk.x = (unsigned)f2bf(acc[m][n][0]) | ((unsigned)f2bf(acc[m][n][1]) << 16);
                pk.y = (unsigned)f2bf(acc[m][n][2]) | ((unsigned)f2bf(acc[m][n][3]) << 16);
                *reinterpret_cast<uint2*>(lT + r * S128 + h) = pk;
            }
    }
    __syncthreads();
    // G_b: A[q][r] = sum_h EN2[h][q] * T[h][r]; waves 0..2, m-tile = wv
    if (wv < 3) {
        const int q0 = wv * 16;
        f32x4 acc[3] = {};
        for (int kk = 0; kk < 4; ++kk) {
            bf16x8 a = frag(lW2 + (q0 + row) * S128 + kk * 32 + kof);
            for (int n = 0; n < 3; ++n) {
                bf16x8 b = frag(lT + (n * 16 + row) * S128 + kk * 32 + kof);
                acc[n] = mfma16(a, b, acc[n]);
            }
        }
        u16* tp = t + (size_t)(bc * 128 + d) * QR;
        for (int n = 0; n < 3; ++n)
            for (int j = 0; j < 4; ++j)
                tp[(q0 + quad * 4 + j) * 48 + n * 16 + row] = f2bf(acc[n][j]);
    }
}

// ---------------------------------------------------------------- kM
// u[bc][d'][q][r] = sum_d M[d'][d] * t[bc][d][q][r]
// grid (qr-tiles 36, bc 16), block 256. GEMM m=d'(128) x n=qr(64), K=128.
// M read directly from global (32 KB, L2-hot) as A-frags; t staged in LDS.
__global__ __launch_bounds__(256) void kM(const u16* __restrict__ t,
                                          const u16* __restrict__ Mw,
                                          u16* __restrict__ u) {
    __shared__ u16 lB[64 * S128];    // [qr_local][d]  (B n-major, k=d contig)
    const int bc = blockIdx.y, qr0 = blockIdx.x * 64;
    const int tid = threadIdx.x, lane = tid & 63, wv = tid >> 6, quad = lane >> 4;
    const int row = lane & 15, kof = quad * 8;

    // stage t tile [d=128][qr 64] -> lB[qr][d] (transpose via u16 writes; 16 KB)
    {
        const u16* tp = t + (size_t)bc * (128 * QR) + qr0 + (tid & 7) * 8;
        const int d0 = tid >> 3;                  // 0..31
        for (int g = 0; g < 4; ++g) {
            int dd = d0 + g * 32;
            u16 v[8];
            *reinterpret_cast<float4*>(v) = *reinterpret_cast<const float4*>(tp + (size_t)dd * QR);
            for (int j = 0; j < 8; ++j) lB[((tid & 7) * 8 + j) * S128 + dd] = v[j];
        }
    }
    __syncthreads();
    const int m0 = wv * 32;
    f32x4 acc[2][4] = {};
    for (int kk = 0; kk < 4; ++kk) {
        bf16x8 a[2], b[4];
        for (int n = 0; n < 4; ++n)
            b[n] = frag(lB + (n * 16 + row) * S128 + kk * 32 + kof);
        for (int m = 0; m < 2; ++m)
            a[m] = frag(Mw + (m0 + m * 16 + row) * 128 + kk * 32 + kof);
        for (int m = 0; m < 2; ++m)
            for (int n = 0; n < 4; ++n) acc[m][n] = mfma16(a[m], b[n], acc[m][n]);
    }
    u16* up = u + (size_t)bc * (128 * QR) + qr0;
    for (int m = 0; m < 2; ++m)
        for (int n = 0; n < 4; ++n)
            for (int j = 0; j < 4; ++j) {
                int dp = m0 + m * 16 + quad * 4 + j;
                up[(size_t)dp * QR + n * 16 + row] = f2bf(acc[m][n][j]);
            }
}

// ---------------------------------------------------------------- kDec
// out[bc][d'][h'][w'] = sum_r (sum_q DE2[q][h'] u[bc][d'][q][r]) * DE1[r][w']
// grid (d'=128, bc=16), block 256 = 4 waves, 2 barriers, LDS 62 KB.
__global__ __launch_bounds__(256) void kDec(const u16* __restrict__ u,
                                            const float* __restrict__ DE2,
                                            const float* __restrict__ DE1,
                                            float* __restrict__ out) {
    __shared__ u16 lU  [48 * S64];   // u^T [r][q pad64]  (B n-major, k=q contig)
    __shared__ u16 lV  [128 * S64];  // V [h'][r pad64]   (A rows, k=r contig)
    __shared__ u16 lWD2[128 * S64];  // DE2t [h'][q pad64] (A rows, k=q contig)
    __shared__ u16 lWD1[128 * S64];  // DE1t [w'][r pad64] (B n-major, k=r contig)
    const int bc = blockIdx.y, dp = blockIdx.x;
    const int tid = threadIdx.x, lane = tid & 63, wv = tid >> 6, quad = lane >> 4;
    const int row = lane & 15, kof = quad * 8;

    // zero K-padding (cols 48..63 of all four tiles' K dims)
    for (int i = tid; i < 48 * 16; i += 256)  lU[(i >> 4) * S64 + 48 + (i & 15)] = 0;
    for (int i = tid; i < 128 * 16; i += 256) {
        int rr = (i >> 4) * S64 + 48 + (i & 15);
        lV[rr] = 0; lWD2[rr] = 0; lWD1[rr] = 0;
    }
    // Convert DE2[q=48][h=128] -> lWD2[h][q] and DE1[r=48][w=128] -> lWD1[w][r].
    for (int i = tid; i < 1536; i += 256) {
        int q = i >> 5, h0 = (i & 31) * 4;
        float4 v = *reinterpret_cast<const float4*>(DE2 + q * 128 + h0);
        lWD2[(h0 + 0) * S64 + q] = f2bf(v.x);
        lWD2[(h0 + 1) * S64 + q] = f2bf(v.y);
        lWD2[(h0 + 2) * S64 + q] = f2bf(v.z);
        lWD2[(h0 + 3) * S64 + q] = f2bf(v.w);
        float4 w = *reinterpret_cast<const float4*>(DE1 + q * 128 + h0);
        lWD1[(h0 + 0) * S64 + q] = f2bf(w.x);
        lWD1[(h0 + 1) * S64 + q] = f2bf(w.y);
        lWD1[(h0 + 2) * S64 + q] = f2bf(w.z);
        lWD1[(h0 + 3) * S64 + q] = f2bf(w.w);
    }
    // stage u[bc][d'][q][r] (4.6 KB) -> lU[r][q] transposed
    {
        const u16* sp = u + (size_t)(bc * 128 + dp) * QR;
        for (int i = tid; i < 288; i += 256) {
            u16 v[8];
            *reinterpret_cast<float4*>(v) = *reinterpret_cast<const float4*>(sp + i * 8);
            int q = i / 6, rb = (i % 6) * 8;
            for (int j = 0; j < 8; ++j) lU[(rb + j) * S64 + q] = v[j];
        }
    }
    __syncthreads();
    // G_a: V[h'][r] = sum_q DE2[q][h'] * u[q][r]; wave: h'-rows [wv*32,+32), K=64
    {
        const int h0 = wv * 32;
        f32x4 acc[2][3] = {};
        for (int kk = 0; kk < 2; ++kk) {
            bf16x8 b[3];
            for (int n = 0; n < 3; ++n)
                b[n] = frag(lU + (n * 16 + row) * S64 + kk * 32 + kof);
            for (int m = 0; m < 2; ++m) {
                bf16x8 a = frag(lWD2 + (h0 + m * 16 + row) * S64 + kk * 32 + kof);
                for (int n = 0; n < 3; ++n) acc[m][n] = mfma16(a, b[n], acc[m][n]);
            }
        }
        for (int m = 0; m < 2; ++m)
            for (int n = 0; n < 3; ++n)
                for (int j = 0; j < 4; ++j)
                    lV[(h0 + m * 16 + quad * 4 + j) * S64 + n * 16 + row] = f2bf(acc[m][n][j]);
    }
    __syncthreads();
    // G_b: out[h'][w'] = sum_r V[h'][r] * DE1[r][w']; K=64, direct fp32 stores
    {
        const int h0 = wv * 32;
        f32x4 acc[2][8] = {};
        for (int kk = 0; kk < 2; ++kk) {
            bf16x8 a[2], b[8];
            for (int n = 0; n < 8; ++n)
                b[n] = frag(lWD1 + (n * 16 + row) * S64 + kk * 32 + kof);
            for (int m = 0; m < 2; ++m)
                a[m] = frag(lV + (h0 + m * 16 + row) * S64 + kk * 32 + kof);
            for (int m = 0; m < 2; ++m)
                for (int n = 0; n < 8; ++n) acc[m][n] = mfma16(a[m], b[n], acc[m][n]);
        }
        float* ob = out + (size_t)bc * L3V + (size_t)dp * HW;
        for (int m = 0; m < 2; ++m)
            for (int n = 0; n < 8; ++n)
                for (int j = 0; j < 4; ++j)
                    ob[(h0 + m * 16 + quad * 4 + j) * 128 + n * 16 + row] = acc[m][n][j];
    }
}

// ---------------------------------------------------------------- launch
extern "C" void kernel_launch(void* const* d_in, const int* in_sizes, int n_in,
                              void* d_out, int out_size, void* d_ws, size_t ws_size,
                              hipStream_t stream) {
    const float* x   = (const float*)d_in[0];
    const float* EN3 = (const float*)d_in[1];
    const float* EN2 = (const float*)d_in[2];
    const float* EN1 = (const float*)d_in[3];
    const float* DE3 = (const float*)d_in[4];
    const float* DE2 = (const float*)d_in[5];
    const float* DE1 = (const float*)d_in[6];
    float* out = (float*)d_out;

    // ws (bytes): t @0 (9,437,184), u @+9437184 (9,437,184), Mw @+18874368 (32 KB)
    u16* t  = (u16*)d_ws;
    u16* u  = (u16*)((char*)d_ws + 9437184);
    u16* Mw = (u16*)((char*)d_ws + 18874368);

    kEnc<<<dim3(128, 16), 256, 0, stream>>>(x, EN1, EN2, EN3, DE3, Mw, t);
    kM  <<<dim3(36, 16),  256, 0, stream>>>(t, Mw, u);
    kDec<<<dim3(128, 16), 256, 0, stream>>>(u, DE2, DE1, out);
}

// Round 5
// 279.758 us; speedup vs baseline: 1.2451x; 1.0164x over previous
//
#include <hip/hip_runtime.h>

// WaveMaskEncoder — 3-dispatch M-collapsed pipeline, high-occupancy kDec.
//   kEnc: t[bc,d,q,r] = EN2^T . (x[bc,d,:,:] . EN1)      (134 MB R, 9.4 MB W)
//         A-operand read DIRECTLY from global x (in-reg bf16 cvt);
//         EN1/EN2 converted in-block to LDS.
//         Hidden side-jobs: d==0 blocks build M = EN3.DE3 (bf16);
//         (d==1,bc==0) builds DE2t table; (d==2,bc==0) builds DE1t table.
//   kM  : u[bc,d',q,r] = sum_d M[d'][d] t[bc,d,q,r]  (M via global L2-hot frags)
//   kDec: out[bc,d',h',w'] = (DE2^T . u[bc,d']) . DE1    (9.4 R, 134 MB W)
//         weight frags from global bf16 tables (L2-hot), LDS 25 KB -> 6 blk/CU.
//
// MFMA 16x16x32 bf16 layouts (HW-verified per docs m89/m120):
//   A[m][k]: m = lane&15, k = (lane>>4)*8 + j   (8 contiguous k per lane)
//   B[k][n]: n = lane&15, k = (lane>>4)*8 + j   (n-major, k-contig storage)
//   C/D:     col = lane&15, row = (lane>>4)*4 + reg

#define LDIM 128
#define NDIM 48
#define HW   (LDIM * LDIM)     // 16384
#define L3V  (LDIM * HW)       // 2097152
#define QR   2304              // 48*48

typedef __bf16 bf16x8 __attribute__((ext_vector_type(8)));
typedef float  f32x4  __attribute__((ext_vector_type(4)));
typedef unsigned short u16;

// LDS row strides (u16 units); multiples of 8 u16 = 16 B for b128 alignment.
#define S128 136
#define S64  72

__device__ __forceinline__ u16 f2bf(float f) {   // fp32 -> bf16 RNE
    unsigned int u = __builtin_bit_cast(unsigned int, f);
    return (u16)((u + 0x7fffu + ((u >> 16) & 1u)) >> 16);
}
__device__ __forceinline__ bf16x8 frag(const u16* p) {
    return *reinterpret_cast<const bf16x8*>(p);
}
__device__ __forceinline__ f32x4 mfma16(bf16x8 a, bf16x8 b, f32x4 c) {
    return __builtin_amdgcn_mfma_f32_16x16x32_bf16(a, b, c, 0, 0, 0);
}

// ---------------------------------------------------------------- kEnc
// t[(bc*128+d)][q][r] = sum_h EN2[h][q] * (sum_w x[bc][d][h][w] EN1[w][r])
// grid (d=128, bc=16), block 256 = 4 waves, 2 barriers, LDS 39 KB.
__global__ __launch_bounds__(256) void kEnc(const float* __restrict__ x,
                                            const float* __restrict__ EN1,
                                            const float* __restrict__ EN2,
                                            const float* __restrict__ EN3,
                                            const float* __restrict__ DE3,
                                            const float* __restrict__ DE2,
                                            const float* __restrict__ DE1,
                                            u16* __restrict__ Mw,
                                            u16* __restrict__ Wd,
                                            u16* __restrict__ t) {
    __shared__ u16 lW1[48 * S128];   // EN1t [r][w]  (B n-major, k=w contig)
    __shared__ u16 lW2[48 * S128];   // EN2t [q][h]  (A rows,   k=h contig)
    __shared__ u16 lT [48 * S128];   // T    [r][h]  (B n-major, k=h contig)
    const int bc = blockIdx.y, d = blockIdx.x;
    const int tid = threadIdx.x, lane = tid & 63, wv = tid >> 6, quad = lane >> 4;
    const int row = lane & 15, kof = quad * 8;

    // ---- Side job 1 (16 blocks, d==0): build M rows [bc*8, bc*8+8).
    if (d == 0) {
        const int dd = tid & 127, sub = tid >> 7;
        const int dpb = bc * 8 + sub;
        float s0 = 0.f, s1 = 0.f, s2 = 0.f, s3 = 0.f;
        for (int p = 0; p < 48; ++p) {
            float e = EN3[dd * 48 + p];
            const float* dr = DE3 + p * 128 + dpb;
            s0 += e * dr[0];
            s1 += e * dr[2];
            s2 += e * dr[4];
            s3 += e * dr[6];
        }
        Mw[(dpb + 0) * 128 + dd] = f2bf(s0);
        Mw[(dpb + 2) * 128 + dd] = f2bf(s1);
        Mw[(dpb + 4) * 128 + dd] = f2bf(s2);
        Mw[(dpb + 6) * 128 + dd] = f2bf(s3);
    }
    // ---- Side job 2: DE2t table [h'=128][q=64 pad0] (one block)
    else if (d == 1 && bc == 0) {
        for (int i = tid; i < 128 * 48; i += 256) {
            int q = i >> 7, h = i & 127;             // coalesced DE2 reads
            Wd[h * 64 + q] = f2bf(DE2[q * 128 + h]);
        }
        for (int i = tid; i < 128 * 16; i += 256) {  // zero pad q=48..63
            int h = i >> 4;
            Wd[h * 64 + 48 + (i & 15)] = 0;
        }
    }
    // ---- Side job 3: DE1t table [w'=128][r=64 pad0] (one block)
    else if (d == 2 && bc == 0) {
        for (int i = tid; i < 128 * 48; i += 256) {
            int r = i >> 7, w = i & 127;
            Wd[8192 + w * 64 + r] = f2bf(DE1[r * 128 + w]);
        }
        for (int i = tid; i < 128 * 16; i += 256) {
            int w = i >> 4;
            Wd[8192 + w * 64 + 48 + (i & 15)] = 0;
        }
    }

    // Convert EN1[w=128][r=48] -> lW1[r][w] and EN2[h=128][q=48] -> lW2[q][h].
    for (int i = tid; i < 1536; i += 256) {
        int w = i / 12, g = i - w * 12, r0 = g * 4;
        float4 v = *reinterpret_cast<const float4*>(EN1 + w * 48 + r0);
        lW1[(r0 + 0) * S128 + w] = f2bf(v.x);
        lW1[(r0 + 1) * S128 + w] = f2bf(v.y);
        lW1[(r0 + 2) * S128 + w] = f2bf(v.z);
        lW1[(r0 + 3) * S128 + w] = f2bf(v.w);
        float4 u = *reinterpret_cast<const float4*>(EN2 + w * 48 + r0);
        lW2[(r0 + 0) * S128 + w] = f2bf(u.x);
        lW2[(r0 + 1) * S128 + w] = f2bf(u.y);
        lW2[(r0 + 2) * S128 + w] = f2bf(u.z);
        lW2[(r0 + 3) * S128 + w] = f2bf(u.w);
    }
    __syncthreads();
    // G_a: T[h][r] = sum_w S[h][w] * EN1[w][r]; wave: h-rows [wv*32,+32).
    // A-frags straight from global x (fp32 -> bf16 in regs); B from lW1.
    {
        const float* xp = x + (size_t)bc * L3V + (size_t)d * HW;
        const int h0 = wv * 32;
        f32x4 acc[2][3] = {};
        for (int kk = 0; kk < 4; ++kk) {
            bf16x8 b[3];
            for (int n = 0; n < 3; ++n)
                b[n] = frag(lW1 + (n * 16 + row) * S128 + kk * 32 + kof);
            for (int m = 0; m < 2; ++m) {
                const float* ap = xp + (h0 + m * 16 + row) * 128 + kk * 32 + kof;
                float4 v0 = *reinterpret_cast<const float4*>(ap);
                float4 v1 = *reinterpret_cast<const float4*>(ap + 4);
                u16 av[8];
                av[0] = f2bf(v0.x); av[1] = f2bf(v0.y); av[2] = f2bf(v0.z); av[3] = f2bf(v0.w);
                av[4] = f2bf(v1.x); av[5] = f2bf(v1.y); av[6] = f2bf(v1.z); av[7] = f2bf(v1.w);
                bf16x8 a = *reinterpret_cast<bf16x8*>(av);
                for (int n = 0; n < 3; ++n) acc[m][n] = mfma16(a, b[n], acc[m][n]);
            }
        }
        // write lT[r][h]; 4 regs = 4 consecutive h -> packed 8B write
        for (int m = 0; m < 2; ++m)
            for (int n = 0; n < 3; ++n) {
                int r = n * 16 + row, h = h0 + m * 16 + quad * 4;
                uint2 pk;
                pk.x = (unsigned)f2bf(acc[m][n][0]) | ((unsigned)f2bf(acc[m][n][1]) << 16);
                pk.y = (unsigned)f2bf(acc[m][n][2]) | ((unsigned)f2bf(acc[m][n][3]) << 16);
                *reinterpret_cast<uint2*>(lT + r * S128 + h) = pk;
            }
    }
    __syncthreads();
    // G_b: A[q][r] = sum_h EN2[h][q] * T[h][r]; waves 0..2, m-tile = wv
    if (wv < 3) {
        const int q0 = wv * 16;
        f32x4 acc[3] = {};
        for (int kk = 0; kk < 4; ++kk) {
            bf16x8 a = frag(lW2 + (q0 + row) * S128 + kk * 32 + kof);
            for (int n = 0; n < 3; ++n) {
                bf16x8 b = frag(lT + (n * 16 + row) * S128 + kk * 32 + kof);
                acc[n] = mfma16(a, b, acc[n]);
            }
        }
        u16* tp = t + (size_t)(bc * 128 + d) * QR;
        for (int n = 0; n < 3; ++n)
            for (int j = 0; j < 4; ++j)
                tp[(q0 + quad * 4 + j) * 48 + n * 16 + row] = f2bf(acc[n][j]);
    }
}

// ---------------------------------------------------------------- kM
// u[bc][d'][q][r] = sum_d M[d'][d] * t[bc][d][q][r]
// grid (qr-tiles 36, bc 16), block 256. GEMM m=d'(128) x n=qr(64), K=128.
// M read directly from global (32 KB, L2-hot) as A-frags; t staged in LDS.
__global__ __launch_bounds__(256) void kM(const u16* __restrict__ t,
                                          const u16* __restrict__ Mw,
                                          u16* __restrict__ u) {
    __shared__ u16 lB[64 * S128];    // [qr_local][d]  (B n-major, k=d contig)
    const int bc = blockIdx.y, qr0 = blockIdx.x * 64;
    const int tid = threadIdx.x, lane = tid & 63, wv = tid >> 6, quad = lane >> 4;
    const int row = lane & 15, kof = quad * 8;

    // stage t tile [d=128][qr 64] -> lB[qr][d] (transpose via u16 writes; 16 KB)
    {
        const u16* tp = t + (size_t)bc * (128 * QR) + qr0 + (tid & 7) * 8;
        const int d0 = tid >> 3;                  // 0..31
        for (int g = 0; g < 4; ++g) {
            int dd = d0 + g * 32;
            u16 v[8];
            *reinterpret_cast<float4*>(v) = *reinterpret_cast<const float4*>(tp + (size_t)dd * QR);
            for (int j = 0; j < 8; ++j) lB[((tid & 7) * 8 + j) * S128 + dd] = v[j];
        }
    }
    __syncthreads();
    const int m0 = wv * 32;
    f32x4 acc[2][4] = {};
    for (int kk = 0; kk < 4; ++kk) {
        bf16x8 a[2], b[4];
        for (int n = 0; n < 4; ++n)
            b[n] = frag(lB + (n * 16 + row) * S128 + kk * 32 + kof);
        for (int m = 0; m < 2; ++m)
            a[m] = frag(Mw + (m0 + m * 16 + row) * 128 + kk * 32 + kof);
        for (int m = 0; m < 2; ++m)
            for (int n = 0; n < 4; ++n) acc[m][n] = mfma16(a[m], b[n], acc[m][n]);
    }
    u16* up = u + (size_t)bc * (128 * QR) + qr0;
    for (int m = 0; m < 2; ++m)
        for (int n = 0; n < 4; ++n)
            for (int j = 0; j < 4; ++j) {
                int dp = m0 + m * 16 + quad * 4 + j;
                up[(size_t)dp * QR + n * 16 + row] = f2bf(acc[m][n][j]);
            }
}

// ---------------------------------------------------------------- kDec
// out[bc][d'][h'][w'] = sum_r (sum_q DE2[q][h'] u[bc][d'][q][r]) * DE1[r][w']
// grid (d'=128, bc=16), block 256 = 4 waves, 2 barriers, LDS 25 KB (6 blk/CU).
// Weight frags read from global bf16 tables Wd (32 KB, L2-hot).
__global__ __launch_bounds__(256) void kDec(const u16* __restrict__ u,
                                            const u16* __restrict__ Wd,
                                            float* __restrict__ out) {
    __shared__ u16 lU[48 * S64];     // u^T [r][q pad64]  (B n-major, k=q contig)
    __shared__ u16 lV[128 * S64];    // V [h'][r pad64]   (A rows, k=r contig)
    const u16* WD2 = Wd;             // DE2t [h'=128][q=64 pad0]
    const u16* WD1 = Wd + 8192;      // DE1t [w'=128][r=64 pad0]
    const int bc = blockIdx.y, dp = blockIdx.x;
    const int tid = threadIdx.x, lane = tid & 63, wv = tid >> 6, quad = lane >> 4;
    const int row = lane & 15, kof = quad * 8;

    // zero K-padding (q=48..63 of lU, r=48..63 of lV)
    for (int i = tid; i < 48 * 16; i += 256)  lU[(i >> 4) * S64 + 48 + (i & 15)] = 0;
    for (int i = tid; i < 128 * 16; i += 256) lV[(i >> 4) * S64 + 48 + (i & 15)] = 0;
    // stage u[bc][d'][q][r] (4.6 KB) -> lU[r][q] transposed
    {
        const u16* sp = u + (size_t)(bc * 128 + dp) * QR;
        for (int i = tid; i < 288; i += 256) {
            u16 v[8];
            *reinterpret_cast<float4*>(v) = *reinterpret_cast<const float4*>(sp + i * 8);
            int q = i / 6, rb = (i % 6) * 8;
            for (int j = 0; j < 8; ++j) lU[(rb + j) * S64 + q] = v[j];
        }
    }
    __syncthreads();
    // G_a: V[h'][r] = sum_q DE2[q][h'] * u[q][r]; wave: h'-rows [wv*32,+32), K=64
    {
        const int h0 = wv * 32;
        f32x4 acc[2][3] = {};
        for (int kk = 0; kk < 2; ++kk) {
            bf16x8 b[3];
            for (int n = 0; n < 3; ++n)
                b[n] = frag(lU + (n * 16 + row) * S64 + kk * 32 + kof);
            for (int m = 0; m < 2; ++m) {
                bf16x8 a = frag(WD2 + (h0 + m * 16 + row) * 64 + kk * 32 + kof);
                for (int n = 0; n < 3; ++n) acc[m][n] = mfma16(a, b[n], acc[m][n]);
            }
        }
        for (int m = 0; m < 2; ++m)
            for (int n = 0; n < 3; ++n)
                for (int j = 0; j < 4; ++j)
                    lV[(h0 + m * 16 + quad * 4 + j) * S64 + n * 16 + row] = f2bf(acc[m][n][j]);
    }
    __syncthreads();
    // G_b: out[h'][w'] = sum_r V[h'][r] * DE1[r][w']; K=64, direct fp32 stores
    {
        const int h0 = wv * 32;
        f32x4 acc[2][8] = {};
        for (int kk = 0; kk < 2; ++kk) {
            bf16x8 a[2], b[8];
            for (int n = 0; n < 8; ++n)
                b[n] = frag(WD1 + (n * 16 + row) * 64 + kk * 32 + kof);
            for (int m = 0; m < 2; ++m)
                a[m] = frag(lV + (h0 + m * 16 + row) * S64 + kk * 32 + kof);
            for (int m = 0; m < 2; ++m)
                for (int n = 0; n < 8; ++n) acc[m][n] = mfma16(a[m], b[n], acc[m][n]);
        }
        float* ob = out + (size_t)bc * L3V + (size_t)dp * HW;
        for (int m = 0; m < 2; ++m)
            for (int n = 0; n < 8; ++n)
                for (int j = 0; j < 4; ++j)
                    ob[(h0 + m * 16 + quad * 4 + j) * 128 + n * 16 + row] = acc[m][n][j];
    }
}

// ---------------------------------------------------------------- launch
extern "C" void kernel_launch(void* const* d_in, const int* in_sizes, int n_in,
                              void* d_out, int out_size, void* d_ws, size_t ws_size,
                              hipStream_t stream) {
    const float* x   = (const float*)d_in[0];
    const float* EN3 = (const float*)d_in[1];
    const float* EN2 = (const float*)d_in[2];
    const float* EN1 = (const float*)d_in[3];
    const float* DE3 = (const float*)d_in[4];
    const float* DE2 = (const float*)d_in[5];
    const float* DE1 = (const float*)d_in[6];
    float* out = (float*)d_out;

    // ws (bytes): t @0 (9,437,184), u @+9437184 (9,437,184),
    //             Mw @+18874368 (32 KB), Wd @+18907136 (32 KB)
    u16* t  = (u16*)d_ws;
    u16* u  = (u16*)((char*)d_ws + 9437184);
    u16* Mw = (u16*)((char*)d_ws + 18874368);
    u16* Wd = (u16*)((char*)d_ws + 18907136);

    kEnc<<<dim3(128, 16), 256, 0, stream>>>(x, EN1, EN2, EN3, DE3, DE2, DE1, Mw, Wd, t);
    kM  <<<dim3(36, 16),  256, 0, stream>>>(t, Mw, u);
    kDec<<<dim3(128, 16), 256, 0, stream>>>(u, Wd, out);
}